// Round 4
// baseline (34105.722 us; speedup 1.0000x reference)
//
#include <hip/hip_runtime.h>
#include <hip/hip_bf16.h>

// ---------------- problem dims ----------------
#define TT   512
#define DIN  1024
#define DH   2048
#define DOUT 1024

// ---------------- launch shape ----------------
#define NWG  256     // one WG per CU; WG g owns h-rows [8g, 8g+8)
#define NTHR 512     // 8 waves; wave w owns row 8g+w
#define RPW  8       // DH / NWG

typedef unsigned int u32;

// ---- scratch in device globals (loader-allocated; d_ws unknown size) ----
__device__ u32   gP1[NWG];
__device__ u32   gP2[NWG];
__device__ float gH1[2 * DH];
__device__ float gH2[2 * DH];

__device__ __forceinline__ float wave_sum(float v) {
  #pragma unroll
  for (int off = 32; off > 0; off >>= 1) v += __shfl_down(v, off, 64);
  return v; // lane 0 holds the sum
}

// Wait until P[c] >= t for all c in [0, NWG). Thread i polls P[i] with
// agent-scope acquire loads (device-coherent across the non-coherent
// per-XCD L2s). Counters are monotonic within a launch -> no ABA hazard.
__device__ __forceinline__ void wait_ge(u32* P, u32 t, int tid) {
  bool done = false;
  for (;;) {
    bool mine = true;
    if (tid < NWG && !done) {
      u32 v = __hip_atomic_load(&P[tid], __ATOMIC_ACQUIRE,
                                __HIP_MEMORY_SCOPE_AGENT);
      done = (v >= t);
      mine = done;
    }
    if (__syncthreads_and(mine ? 1 : 0)) break;
    __builtin_amdgcn_s_sleep(2);  // back off; reduce L3 poll pressure
  }
}

// Stage a 2048-float h-vector from the coherent point into LDS.
// Thread tid handles 4 stride-512 elements: coalesced, bank-conflict-free.
__device__ __forceinline__ void stage(float* dst, const float* src, int tid) {
  #pragma unroll
  for (int i = 0; i < DH / NTHR; ++i) {
    int idx = tid + i * NTHR;
    dst[idx] = __hip_atomic_load((float*)(src + idx), __ATOMIC_RELAXED,
                                 __HIP_MEMORY_SCOPE_AGENT);
  }
}

// Zero the progress counters before each main-kernel run (stream-ordered;
// device globals persist across graph replays).
__global__ void init_kernel() {
  int i = threadIdx.x;
  if (i < NWG) { gP1[i] = 0u; gP2[i] = 0u; }
}

__device__ __forceinline__ float dot4(float4 a, float4 b) {
  return a.x * b.x + a.y * b.y + a.z * b.z + a.w * b.w;
}

__global__ __launch_bounds__(NTHR, 2)
void rnn2_kernel(const float* __restrict__ X,
                 const float* __restrict__ Wa, const float* __restrict__ ba,
                 const float* __restrict__ Wb, const float* __restrict__ bb,
                 const float* __restrict__ Wc, const float* __restrict__ bc,
                 const float* __restrict__ Wd, const float* __restrict__ bd,
                 const float* __restrict__ Wo, const float* __restrict__ bo,
                 float* __restrict__ out)
{
  const int g   = blockIdx.x;
  const int tid = threadIdx.x;
  const int w   = tid >> 6;   // wave index = my h-row within the WG
  const int l   = tid & 63;   // lane
  const int r   = g * RPW + w;

  __shared__ float sH1p[DH];  // h1[t-1]
  __shared__ float sH2p[DH];  // h2[t-1]
  __shared__ float sH1c[DH];  // h1[t]  (and h2[T] in the epilogue)

  // ---- one-time: weights for my row into registers (fp32, float4-wide) ----
  // lane l owns elements 4l + 256j: float4 global loads are coalesced, and
  // the matching LDS b128 reads hit the 8-phase minimum (no extra conflicts).
  float4 wA[4], wB[8], wC[8], wD[8];
  {
    const float4* p = (const float4*)(Wa + (size_t)r * DIN);
    #pragma unroll
    for (int j = 0; j < 4; ++j) wA[j] = p[l + 64 * j];
  }
  {
    const float4* p = (const float4*)(Wb + (size_t)r * DH);
    #pragma unroll
    for (int j = 0; j < 8; ++j) wB[j] = p[l + 64 * j];
  }
  {
    const float4* p = (const float4*)(Wc + (size_t)r * DH);
    #pragma unroll
    for (int j = 0; j < 8; ++j) wC[j] = p[l + 64 * j];
  }
  {
    const float4* p = (const float4*)(Wd + (size_t)r * DH);
    #pragma unroll
    for (int j = 0; j < 8; ++j) wD[j] = p[l + 64 * j];
  }
  const float bias1 = ba[r] + bb[r];
  const float bias2 = bc[r] + bd[r];

  // steps t = 1..TT ; h*[0] == 0 handled by skipping recurrent terms at t==1.
  // H slots double-buffered: step t lives in slot t&1. Safe: a WG writes
  // H*[t&1] (slot of t-2) only after all P2 >= t-1, and every WG staged the
  // t-2 slot to LDS before publishing P2 = t-1 (max skew = 1 step).
  for (int t = 1; t <= TT; ++t) {
    // ---- A.x[t-1]: no cross-WG dependency -> compute before any wait ----
    float accA = 0.f;
    {
      const float4* px = (const float4*)(X + (size_t)(t - 1) * DIN);
      #pragma unroll
      for (int j = 0; j < 4; ++j) accA += dot4(wA[j], px[l + 64 * j]);
    }

    if (t > 1) {
      // P2[c] >= t-1 proves BOTH h1[t-1] and h2[t-1] complete + visible.
      wait_ge(gP2, t - 1, tid);
      stage(sH1p, gH1 + (size_t)((t - 1) & 1) * DH, tid);
      stage(sH2p, gH2 + (size_t)((t - 1) & 1) * DH, tid);
      __syncthreads();
    }

    // ---- layer 1: h1[t][r] = tanh(A.x + B.h1[t-1] + bias1) ----
    float acc = accA;
    if (t > 1) {
      const float4* ph = (const float4*)sH1p;
      #pragma unroll
      for (int j = 0; j < 8; ++j) acc += dot4(wB[j], ph[l + 64 * j]);
    }
    acc = wave_sum(acc);
    if (l == 0)
      __hip_atomic_store(gH1 + (size_t)(t & 1) * DH + r, tanhf(acc + bias1),
                         __ATOMIC_RELAXED, __HIP_MEMORY_SCOPE_AGENT);
    __builtin_amdgcn_fence(__ATOMIC_RELEASE, "agent");  // drain my wave's store
    __syncthreads();                                    // all waves drained
    if (tid == 0)
      __hip_atomic_store(&gP1[g], (u32)t,
                         __ATOMIC_RELEASE, __HIP_MEMORY_SCOPE_AGENT);

    // ---- D.h2[t-1]: independent of h1[t] -> overlap with the P1 wait ----
    float accD = 0.f;
    if (t > 1) {
      const float4* ph = (const float4*)sH2p;
      #pragma unroll
      for (int j = 0; j < 8; ++j) accD += dot4(wD[j], ph[l + 64 * j]);
    }

    // ---- layer 2 needs the FULL h1[t] ----
    wait_ge(gP1, t, tid);
    stage(sH1c, gH1 + (size_t)(t & 1) * DH, tid);
    __syncthreads();

    float acc2 = accD;
    {
      const float4* ph = (const float4*)sH1c;
      #pragma unroll
      for (int j = 0; j < 8; ++j) acc2 += dot4(wC[j], ph[l + 64 * j]);
    }
    acc2 = wave_sum(acc2);
    if (l == 0)
      __hip_atomic_store(gH2 + (size_t)(t & 1) * DH + r, tanhf(acc2 + bias2),
                         __ATOMIC_RELAXED, __HIP_MEMORY_SCOPE_AGENT);
    __builtin_amdgcn_fence(__ATOMIC_RELEASE, "agent");
    __syncthreads();
    if (tid == 0)
      __hip_atomic_store(&gP2[g], (u32)t,
                         __ATOMIC_RELEASE, __HIP_MEMORY_SCOPE_AGENT);
  }

  // ---- epilogue: out = W_h2o2 . h2[TT] + b_h2o2  (4 rows per WG) ----
  wait_ge(gP2, TT, tid);
  stage(sH1c, gH2 + (size_t)(TT & 1) * DH, tid);
  __syncthreads();
  if (w < DOUT / NWG) {
    const int orow = g * (DOUT / NWG) + w;
    const float4* pw = (const float4*)(Wo + (size_t)orow * DH);
    const float4* ph = (const float4*)sH1c;
    float acc = 0.f;
    #pragma unroll
    for (int j = 0; j < 8; ++j) acc += dot4(pw[l + 64 * j], ph[l + 64 * j]);
    acc = wave_sum(acc);
    if (l == 0)
      out[orow] = acc + bo[orow];
  }
}

extern "C" void kernel_launch(void* const* d_in, const int* in_sizes, int n_in,
                              void* d_out, int out_size, void* d_ws, size_t ws_size,
                              hipStream_t stream)
{
  (void)in_sizes; (void)n_in; (void)out_size; (void)d_ws; (void)ws_size;

  // All tensors are fp32 per the reference (rounds 1-3 NaN came from
  // misreading fp32 buffers as bf16 pairs: mantissa bits decoded as bf16
  // exponents -> Inf/NaN in ~1/256 of elements).
  const float* X  = (const float*)d_in[0];
  const float* Wa = (const float*)d_in[1];   // W_i2h1 [H][IN]
  const float* ba = (const float*)d_in[2];
  const float* Wb = (const float*)d_in[3];   // W_h2h1 [H][H]
  const float* bb = (const float*)d_in[4];
  // d_in[5], d_in[6]: W_h2o1 / b_h2o1 — dead code in the reference
  const float* Wc = (const float*)d_in[7];   // W_i2h2 [H][H]
  const float* bc = (const float*)d_in[8];
  const float* Wd = (const float*)d_in[9];   // W_h2h2 [H][H]
  const float* bd = (const float*)d_in[10];
  const float* Wo = (const float*)d_in[11];  // W_h2o2 [OUT][H]
  const float* bo = (const float*)d_in[12];
  float* out = (float*)d_out;

  init_kernel<<<dim3(1), dim3(NWG), 0, stream>>>();

  void* args[] = { &X, &Wa, &ba, &Wb, &bb, &Wc, &bc, &Wd, &bd, &Wo, &bo, &out };
  hipLaunchCooperativeKernel((void*)rnn2_kernel, dim3(NWG), dim3(NTHR),
                             args, 0, stream);
}

// Round 5
// 3378.241 us; speedup vs baseline: 10.0957x; 10.0957x over previous
//
#include <hip/hip_runtime.h>

// ---------------- problem dims ----------------
#define TT   512
#define DIN  1024
#define DH   2048
#define DOUT 1024

// ---------------- launch shape ----------------
#define NWG  256     // WGs 0..127: layer-1 chain (+epilogue); 128..255: layer-2 chain
#define HALF 128
#define NTHR 512     // 8 waves; each wave owns 2 h-rows of its chain

typedef unsigned int u32;

// ---- scratch in device globals (loader-allocated) ----
// Counters in separate 128-B lines. 4-deep slot ring for each h vector.
__device__ u32   gC1[32];      // h1 chain progress: 128 * completed steps
__device__ u32   gC2[32];      // h2 chain progress
__device__ float gH1[4 * DH];
__device__ float gH2[4 * DH];

__device__ __forceinline__ float dot4(float4 a, float4 b) {
  return a.x * b.x + a.y * b.y + a.z * b.z + a.w * b.w;
}

__device__ __forceinline__ float wave_sum(float v) {
  #pragma unroll
  for (int off = 32; off > 0; off >>= 1) v += __shfl_down(v, off, 64);
  return v; // lane 0 holds the sum
}

// Thread 0 polls both counters with RELAXED sc1 loads (no per-poll cache
// invalidate, no fence), then one barrier releases the WG. Freshness of the
// subsequent h reads is guaranteed because they are themselves sc1 loads
// served at the coherent point (no L1/L2 staleness possible).
__device__ __forceinline__ void poll2(u32 t1, u32 t2, int tid) {
  if (tid == 0) {
    for (;;) {
      u32 a = __hip_atomic_load(&gC1[0], __ATOMIC_RELAXED, __HIP_MEMORY_SCOPE_AGENT);
      u32 b = __hip_atomic_load(&gC2[0], __ATOMIC_RELAXED, __HIP_MEMORY_SCOPE_AGENT);
      if (a >= t1 && b >= t2) break;
      __builtin_amdgcn_s_sleep(4);   // ~256 cyc backoff
    }
  }
  __syncthreads();
}

// Stage a 2048-float h vector from the coherent point into LDS (coalesced).
__device__ __forceinline__ void stage(float* dst, const float* src, int tid) {
  #pragma unroll
  for (int i = 0; i < DH / NTHR; ++i) {
    int idx = tid + i * NTHR;
    dst[idx] = __hip_atomic_load((float*)(src + idx), __ATOMIC_RELAXED,
                                 __HIP_MEMORY_SCOPE_AGENT);
  }
}

// Zero progress counters (device globals persist across graph replays).
__global__ void init_kernel() {
  if (threadIdx.x == 0) {
    __hip_atomic_store(&gC1[0], 0u, __ATOMIC_RELAXED, __HIP_MEMORY_SCOPE_AGENT);
    __hip_atomic_store(&gC2[0], 0u, __ATOMIC_RELAXED, __HIP_MEMORY_SCOPE_AGENT);
  }
}

__global__ __launch_bounds__(NTHR, 2)
void rnn2_kernel(const float* __restrict__ X,
                 const float* __restrict__ Wa, const float* __restrict__ ba,
                 const float* __restrict__ Wb, const float* __restrict__ bb,
                 const float* __restrict__ Wc, const float* __restrict__ bc,
                 const float* __restrict__ Wd, const float* __restrict__ bd,
                 const float* __restrict__ Wo, const float* __restrict__ bo,
                 float* __restrict__ out)
{
  const int g   = blockIdx.x;
  const int tid = threadIdx.x;
  const int w   = tid >> 6;   // wave
  const int l   = tid & 63;   // lane

  __shared__ float sA[DH];
  __shared__ float sB[DH];

  if (g < HALF) {
    // ================= layer-1 chain (+ output epilogue) =================
    const int r0 = g * 16 + 2 * w, r1 = r0 + 1;   // my two h1 rows
    float4 wA0[4], wA1[4], wB0[8], wB1[8], wO[8];
    {
      const float4* p0 = (const float4*)(Wa + (size_t)r0 * DIN);
      const float4* p1 = (const float4*)(Wa + (size_t)r1 * DIN);
      #pragma unroll
      for (int j = 0; j < 4; ++j) { wA0[j] = p0[l + 64 * j]; wA1[j] = p1[l + 64 * j]; }
    }
    {
      const float4* p0 = (const float4*)(Wb + (size_t)r0 * DH);
      const float4* p1 = (const float4*)(Wb + (size_t)r1 * DH);
      #pragma unroll
      for (int j = 0; j < 8; ++j) { wB0[j] = p0[l + 64 * j]; wB1[j] = p1[l + 64 * j]; }
    }
    const int orow = g * 8 + w;                   // my output row
    {
      const float4* p = (const float4*)(Wo + (size_t)orow * DH);
      #pragma unroll
      for (int j = 0; j < 8; ++j) wO[j] = p[l + 64 * j];
    }
    const float b1_0 = ba[r0] + bb[r0];
    const float b1_1 = ba[r1] + bb[r1];
    const float bo_r = bo[orow];

    for (int t = 1; t <= TT; ++t) {
      // A.x[t-1]: no cross-WG dependency — compute before the wait
      float a0 = 0.f, a1 = 0.f;
      {
        const float4* px = (const float4*)(X + (size_t)(t - 1) * DIN);
        #pragma unroll
        for (int j = 0; j < 4; ++j) {
          float4 x4 = px[l + 64 * j];
          a0 += dot4(wA0[j], x4);
          a1 += dot4(wA1[j], x4);
        }
      }
      // need: all h1[t-1] published; slot (t&3) free of h2-chain readers
      const u32 tgt1 = 128u * (u32)(t - 1);
      const u32 tgt2 = (t >= 5) ? 128u * (u32)(t - 4) : 0u;
      poll2(tgt1, tgt2, tid);
      if (t > 1) {
        stage(sA, gH1 + (size_t)((t - 1) & 3) * DH, tid);
        __syncthreads();
        const float4* ph = (const float4*)sA;
        #pragma unroll
        for (int j = 0; j < 8; ++j) {
          float4 h4 = ph[l + 64 * j];
          a0 += dot4(wB0[j], h4);
          a1 += dot4(wB1[j], h4);
        }
      }
      a0 = wave_sum(a0); a1 = wave_sum(a1);
      if (l == 0) {
        float* dst = gH1 + (size_t)(t & 3) * DH;
        __hip_atomic_store(dst + r0, tanhf(a0 + b1_0), __ATOMIC_RELAXED, __HIP_MEMORY_SCOPE_AGENT);
        __hip_atomic_store(dst + r1, tanhf(a1 + b1_1), __ATOMIC_RELAXED, __HIP_MEMORY_SCOPE_AGENT);
      }
      __syncthreads();  // drains all waves' vmcnt -> sc1 stores globally visible
      if (tid == 0)
        __hip_atomic_fetch_add(&gC1[0], 1u, __ATOMIC_RELAXED, __HIP_MEMORY_SCOPE_AGENT);
    }

    // ---- epilogue: out = Wo . h2[TT] + bo (1 row per wave) ----
    poll2(0u, 128u * (u32)TT, tid);
    stage(sA, gH2 + (size_t)(TT & 3) * DH, tid);
    __syncthreads();
    {
      const float4* ph = (const float4*)sA;
      float acc = 0.f;
      #pragma unroll
      for (int j = 0; j < 8; ++j) acc += dot4(wO[j], ph[l + 64 * j]);
      acc = wave_sum(acc);
      if (l == 0) out[orow] = acc + bo_r;
    }
  } else {
    // ========================= layer-2 chain =========================
    const int gg = g - HALF;
    const int r0 = gg * 16 + 2 * w, r1 = r0 + 1;  // my two h2 rows
    float4 wC0[8], wC1[8], wD0[8], wD1[8];
    {
      const float4* p0 = (const float4*)(Wc + (size_t)r0 * DH);
      const float4* p1 = (const float4*)(Wc + (size_t)r1 * DH);
      #pragma unroll
      for (int j = 0; j < 8; ++j) { wC0[j] = p0[l + 64 * j]; wC1[j] = p1[l + 64 * j]; }
    }
    {
      const float4* p0 = (const float4*)(Wd + (size_t)r0 * DH);
      const float4* p1 = (const float4*)(Wd + (size_t)r1 * DH);
      #pragma unroll
      for (int j = 0; j < 8; ++j) { wD0[j] = p0[l + 64 * j]; wD1[j] = p1[l + 64 * j]; }
    }
    const float b2_0 = bc[r0] + bd[r0];
    const float b2_1 = bc[r1] + bd[r1];

    for (int t = 1; t <= TT; ++t) {
      // need: full h1[t]; all h2[t-1]
      poll2(128u * (u32)t, 128u * (u32)(t - 1), tid);
      stage(sA, gH1 + (size_t)(t & 3) * DH, tid);
      if (t > 1) stage(sB, gH2 + (size_t)((t - 1) & 3) * DH, tid);
      __syncthreads();

      float a0 = 0.f, a1 = 0.f;
      {
        const float4* ph = (const float4*)sA;
        #pragma unroll
        for (int j = 0; j < 8; ++j) {
          float4 h4 = ph[l + 64 * j];
          a0 += dot4(wC0[j], h4);
          a1 += dot4(wC1[j], h4);
        }
      }
      if (t > 1) {
        const float4* ph = (const float4*)sB;
        #pragma unroll
        for (int j = 0; j < 8; ++j) {
          float4 h4 = ph[l + 64 * j];
          a0 += dot4(wD0[j], h4);
          a1 += dot4(wD1[j], h4);
        }
      }
      a0 = wave_sum(a0); a1 = wave_sum(a1);
      if (l == 0) {
        float* dst = gH2 + (size_t)(t & 3) * DH;
        __hip_atomic_store(dst + r0, tanhf(a0 + b2_0), __ATOMIC_RELAXED, __HIP_MEMORY_SCOPE_AGENT);
        __hip_atomic_store(dst + r1, tanhf(a1 + b2_1), __ATOMIC_RELAXED, __HIP_MEMORY_SCOPE_AGENT);
      }
      __syncthreads();  // drain sc1 stores before publishing
      if (tid == 0)
        __hip_atomic_fetch_add(&gC2[0], 1u, __ATOMIC_RELAXED, __HIP_MEMORY_SCOPE_AGENT);
    }
  }
}

extern "C" void kernel_launch(void* const* d_in, const int* in_sizes, int n_in,
                              void* d_out, int out_size, void* d_ws, size_t ws_size,
                              hipStream_t stream)
{
  (void)in_sizes; (void)n_in; (void)out_size; (void)d_ws; (void)ws_size;

  const float* X  = (const float*)d_in[0];
  const float* Wa = (const float*)d_in[1];   // W_i2h1 [H][IN]
  const float* ba = (const float*)d_in[2];
  const float* Wb = (const float*)d_in[3];   // W_h2h1 [H][H]
  const float* bb = (const float*)d_in[4];
  // d_in[5], d_in[6]: W_h2o1 / b_h2o1 — dead code in the reference
  const float* Wc = (const float*)d_in[7];   // W_i2h2 [H][H]
  const float* bc = (const float*)d_in[8];
  const float* Wd = (const float*)d_in[9];   // W_h2h2 [H][H]
  const float* bd = (const float*)d_in[10];
  const float* Wo = (const float*)d_in[11];  // W_h2o2 [OUT][H]
  const float* bo = (const float*)d_in[12];
  float* out = (float*)d_out;

  init_kernel<<<dim3(1), dim3(64), 0, stream>>>();

  void* args[] = { &X, &Wa, &ba, &Wb, &bb, &Wc, &bc, &Wd, &bd, &Wo, &bo, &out };
  hipLaunchCooperativeKernel((void*)rnn2_kernel, dim3(NWG), dim3(NTHR),
                             args, 0, stream);
}

// Round 7
// 3171.483 us; speedup vs baseline: 10.7539x; 1.0652x over previous
//
#include <hip/hip_runtime.h>

// ---------------- problem dims ----------------
#define TT   512
#define DIN  1024
#define DH   2048
#define DOUT 1024

// ---------------- launch shape ----------------
#define NWG  256     // WGs 0..127: layer-1 chain (+epilogue); 128..255: layer-2 chain
#define HALF 128
#define NTHR 512     // 8 waves; each wave owns 2 h-rows of its chain
#define RING 8       // H slot ring depth

typedef unsigned int u32;
typedef unsigned long long u64;

// ---- scratch in device globals (loader-allocated) ----
// Per-WG publication slots, packed 2-per-u64 (u64 arrays => native 8-byte
// alignment for the consumers' u64 atomic polls; producers store their own
// u32 half via cast — plain byte-enabled sc1 store, NO RMW serialization).
__device__ u64   gS1q[HALF / 2] __attribute__((aligned(256)));
__device__ u64   gS2q[HALF / 2] __attribute__((aligned(256)));
__device__ float gH1[RING * DH];
__device__ float gH2[RING * DH];

__device__ __forceinline__ float dot4(float4 a, float4 b) {
  return a.x * b.x + a.y * b.y + a.z * b.z + a.w * b.w;
}

__device__ __forceinline__ float wave_sum(float v) {
  #pragma unroll
  for (int off = 32; off > 0; off >>= 1) v += __shfl_down(v, off, 64);
  return v; // lane 0 holds the sum
}

// Parallel fan-in detection: wave 0 waits until all gS1 slots >= t1, wave 1
// until all gS2 slots >= t2 (each lane owns one u64 = 2 packed slots; exits
// as soon as its pair passes). Relaxed sc1 loads: served at the coherent
// point (no staleness), no cache invalidate, no barrier per poll iteration.
__device__ __forceinline__ void wait_chains(u32 t1, u32 t2, int tid) {
  const int w = tid >> 6, l = tid & 63;
  if (w == 0) {
    if (t1) {
      for (;;) {
        u64 v = __hip_atomic_load(&gS1q[l], __ATOMIC_RELAXED,
                                  __HIP_MEMORY_SCOPE_AGENT);
        if ((u32)v >= t1 && (u32)(v >> 32) >= t1) break;
        __builtin_amdgcn_s_sleep(2);
      }
    }
  } else if (w == 1) {
    if (t2) {
      for (;;) {
        u64 v = __hip_atomic_load(&gS2q[l], __ATOMIC_RELAXED,
                                  __HIP_MEMORY_SCOPE_AGENT);
        if ((u32)v >= t2 && (u32)(v >> 32) >= t2) break;
        __builtin_amdgcn_s_sleep(2);
      }
    }
  }
  __syncthreads();
}

// Stage a 2048-float h vector from the coherent point into LDS (coalesced).
__device__ __forceinline__ void stage(float* dst, const float* src, int tid) {
  #pragma unroll
  for (int i = 0; i < DH / NTHR; ++i) {
    int idx = tid + i * NTHR;
    dst[idx] = __hip_atomic_load((float*)(src + idx), __ATOMIC_RELAXED,
                                 __HIP_MEMORY_SCOPE_AGENT);
  }
}

// Zero publication slots with agent-scope stores (plain stores could sit
// dirty in one XCD's L2 and be invisible to the main kernel's sc1 reads).
__global__ void init_kernel() {
  int i = threadIdx.x;
  if (i < HALF / 2) {
    __hip_atomic_store(&gS1q[i], 0ull, __ATOMIC_RELAXED, __HIP_MEMORY_SCOPE_AGENT);
    __hip_atomic_store(&gS2q[i], 0ull, __ATOMIC_RELAXED, __HIP_MEMORY_SCOPE_AGENT);
  }
}

__global__ __launch_bounds__(NTHR, 2)
void rnn2_kernel(const float* __restrict__ X,
                 const float* __restrict__ Wa, const float* __restrict__ ba,
                 const float* __restrict__ Wb, const float* __restrict__ bb,
                 const float* __restrict__ Wc, const float* __restrict__ bc,
                 const float* __restrict__ Wd, const float* __restrict__ bd,
                 const float* __restrict__ Wo, const float* __restrict__ bo,
                 float* __restrict__ out)
{
  const int g   = blockIdx.x;
  const int tid = threadIdx.x;
  const int w   = tid >> 6;   // wave
  const int l   = tid & 63;   // lane

  __shared__ float sA[DH];
  __shared__ float sB[DH];

  if (g < HALF) {
    // ================= layer-1 chain (+ output epilogue) =================
    const int r0 = g * 16 + 2 * w, r1 = r0 + 1;   // my two h1 rows
    float4 wA0[4], wA1[4], wB0[8], wB1[8], wO[8];
    {
      const float4* p0 = (const float4*)(Wa + (size_t)r0 * DIN);
      const float4* p1 = (const float4*)(Wa + (size_t)r1 * DIN);
      #pragma unroll
      for (int j = 0; j < 4; ++j) { wA0[j] = p0[l + 64 * j]; wA1[j] = p1[l + 64 * j]; }
    }
    {
      const float4* p0 = (const float4*)(Wb + (size_t)r0 * DH);
      const float4* p1 = (const float4*)(Wb + (size_t)r1 * DH);
      #pragma unroll
      for (int j = 0; j < 8; ++j) { wB0[j] = p0[l + 64 * j]; wB1[j] = p1[l + 64 * j]; }
    }
    const int orow = g * 8 + w;                   // my output row
    {
      const float4* p = (const float4*)(Wo + (size_t)orow * DH);
      #pragma unroll
      for (int j = 0; j < 8; ++j) wO[j] = p[l + 64 * j];
    }
    const float b1_0 = ba[r0] + bb[r0];
    const float b1_1 = ba[r1] + bb[r1];
    const float bo_r = bo[orow];

    for (int t = 1; t <= TT; ++t) {
      // A.x[t-1]: no cross-WG dependency — compute before the wait
      float a0 = 0.f, a1 = 0.f;
      {
        const float4* px = (const float4*)(X + (size_t)(t - 1) * DIN);
        #pragma unroll
        for (int j = 0; j < 4; ++j) {
          float4 x4 = px[l + 64 * j];
          a0 += dot4(wA0[j], x4);
          a1 += dot4(wA1[j], x4);
        }
      }
      // need: all h1[t-1] published; gH1 slot (t&7) free of h2-chain readers
      wait_chains((u32)(t - 1), (t > RING) ? (u32)(t - RING) : 0u, tid);
      if (t > 1) {
        stage(sA, gH1 + (size_t)((t - 1) & (RING - 1)) * DH, tid);
        __syncthreads();
        const float4* ph = (const float4*)sA;
        #pragma unroll
        for (int j = 0; j < 8; ++j) {
          float4 h4 = ph[l + 64 * j];
          a0 += dot4(wB0[j], h4);
          a1 += dot4(wB1[j], h4);
        }
      }
      a0 = wave_sum(a0); a1 = wave_sum(a1);
      if (l == 0) {
        float* dst = gH1 + (size_t)(t & (RING - 1)) * DH;
        __hip_atomic_store(dst + r0, tanhf(a0 + b1_0), __ATOMIC_RELAXED, __HIP_MEMORY_SCOPE_AGENT);
        __hip_atomic_store(dst + r1, tanhf(a1 + b1_1), __ATOMIC_RELAXED, __HIP_MEMORY_SCOPE_AGENT);
      }
      __syncthreads();  // drains all waves' vmcnt -> sc1 h-stores globally visible
      if (tid == 0)
        __hip_atomic_store((u32*)gS1q + g, (u32)t,
                           __ATOMIC_RELAXED, __HIP_MEMORY_SCOPE_AGENT);
    }

    // ---- epilogue: out = Wo . h2[TT] + bo (1 row per wave) ----
    wait_chains(0u, (u32)TT, tid);
    stage(sA, gH2 + (size_t)(TT & (RING - 1)) * DH, tid);
    __syncthreads();
    {
      const float4* ph = (const float4*)sA;
      float acc = 0.f;
      #pragma unroll
      for (int j = 0; j < 8; ++j) acc += dot4(wO[j], ph[l + 64 * j]);
      acc = wave_sum(acc);
      if (l == 0) out[orow] = acc + bo_r;
    }
  } else {
    // ========================= layer-2 chain =========================
    const int gg = g - HALF;
    const int r0 = gg * 16 + 2 * w, r1 = r0 + 1;  // my two h2 rows
    float4 wC0[8], wC1[8], wD0[8], wD1[8];
    {
      const float4* p0 = (const float4*)(Wc + (size_t)r0 * DH);
      const float4* p1 = (const float4*)(Wc + (size_t)r1 * DH);
      #pragma unroll
      for (int j = 0; j < 8; ++j) { wC0[j] = p0[l + 64 * j]; wC1[j] = p1[l + 64 * j]; }
    }
    {
      const float4* p0 = (const float4*)(Wd + (size_t)r0 * DH);
      const float4* p1 = (const float4*)(Wd + (size_t)r1 * DH);
      #pragma unroll
      for (int j = 0; j < 8; ++j) { wD0[j] = p0[l + 64 * j]; wD1[j] = p1[l + 64 * j]; }
    }
    const float b2_0 = bc[r0] + bd[r0];
    const float b2_1 = bc[r1] + bd[r1];

    for (int t = 1; t <= TT; ++t) {
      // need: full h1[t]; all h2[t-1]
      wait_chains((u32)t, (u32)(t - 1), tid);
      stage(sA, gH1 + (size_t)(t & (RING - 1)) * DH, tid);
      if (t > 1) stage(sB, gH2 + (size_t)((t - 1) & (RING - 1)) * DH, tid);
      __syncthreads();

      float a0 = 0.f, a1 = 0.f;
      {
        const float4* ph = (const float4*)sA;
        #pragma unroll
        for (int j = 0; j < 8; ++j) {
          float4 h4 = ph[l + 64 * j];
          a0 += dot4(wC0[j], h4);
          a1 += dot4(wC1[j], h4);
        }
      }
      if (t > 1) {
        const float4* ph = (const float4*)sB;
        #pragma unroll
        for (int j = 0; j < 8; ++j) {
          float4 h4 = ph[l + 64 * j];
          a0 += dot4(wD0[j], h4);
          a1 += dot4(wD1[j], h4);
        }
      }
      a0 = wave_sum(a0); a1 = wave_sum(a1);
      if (l == 0) {
        float* dst = gH2 + (size_t)(t & (RING - 1)) * DH;
        __hip_atomic_store(dst + r0, tanhf(a0 + b2_0), __ATOMIC_RELAXED, __HIP_MEMORY_SCOPE_AGENT);
        __hip_atomic_store(dst + r1, tanhf(a1 + b2_1), __ATOMIC_RELAXED, __HIP_MEMORY_SCOPE_AGENT);
      }
      __syncthreads();  // drain sc1 h-stores before publishing
      if (tid == 0)
        __hip_atomic_store((u32*)gS2q + gg, (u32)t,
                           __ATOMIC_RELAXED, __HIP_MEMORY_SCOPE_AGENT);
    }
  }
}

extern "C" void kernel_launch(void* const* d_in, const int* in_sizes, int n_in,
                              void* d_out, int out_size, void* d_ws, size_t ws_size,
                              hipStream_t stream)
{
  (void)in_sizes; (void)n_in; (void)out_size; (void)d_ws; (void)ws_size;

  const float* X  = (const float*)d_in[0];
  const float* Wa = (const float*)d_in[1];   // W_i2h1 [H][IN]
  const float* ba = (const float*)d_in[2];
  const float* Wb = (const float*)d_in[3];   // W_h2h1 [H][H]
  const float* bb = (const float*)d_in[4];
  // d_in[5], d_in[6]: W_h2o1 / b_h2o1 — dead code in the reference
  const float* Wc = (const float*)d_in[7];   // W_i2h2 [H][H]
  const float* bc = (const float*)d_in[8];
  const float* Wd = (const float*)d_in[9];   // W_h2h2 [H][H]
  const float* bd = (const float*)d_in[10];
  const float* Wo = (const float*)d_in[11];  // W_h2o2 [OUT][H]
  const float* bo = (const float*)d_in[12];
  float* out = (float*)d_out;

  init_kernel<<<dim3(1), dim3(HALF), 0, stream>>>();

  void* args[] = { &X, &Wa, &ba, &Wb, &bb, &Wc, &bc, &Wd, &bd, &Wo, &bo, &out };
  (void)hipLaunchCooperativeKernel((void*)rnn2_kernel, dim3(NWG), dim3(NTHR),
                                   args, 0, stream);
}

// Round 8
// 2845.604 us; speedup vs baseline: 11.9854x; 1.1145x over previous
//
#include <hip/hip_runtime.h>

// ---------------- problem dims ----------------
#define TT   512
#define DIN  1024
#define DH   2048
#define DOUT 1024

// ---------------- launch shape ----------------
#define NWG   256    // WGs 0..127: h1 chain (+epilogue); 128..255: h2 chain
#define HALF  128
#define NTHR  512    // 8 waves; each wave owns 2 h-rows of its chain
#define NSLOT (TT + 1)

typedef unsigned int u32;
typedef unsigned long long u64;

// One record per h element per step: {epoch (hi 32) | f32 bits (lo 32)}.
// A single u64 relaxed agent-scope store/load is architecturally atomic, so
// data and flag travel in ONE L3 round trip — replacing the old 4-serial-RT
// chain (store drain -> flag store -> flag poll -> data stage).
// Slot t is unique per step (no ring reuse) -> no anti-dependency guards,
// no ABA, provably deadlock-free DAG. ~8.4 MB per chain, L3-resident.
__device__ u64 gR1[NSLOT * DH];   // h1 records
__device__ u64 gR2[NSLOT * DH];   // h2 records

__device__ __forceinline__ float dot4(float4 a, float4 b) {
  return a.x * b.x + a.y * b.y + a.z * b.z + a.w * b.w;
}
__device__ __forceinline__ float wave_sum(float v) {
  #pragma unroll
  for (int off = 32; off > 0; off >>= 1) v += __shfl_down(v, off, 64);
  return v; // lane 0 holds the sum
}
__device__ __forceinline__ u64 ld_rec(const u64* p) {
  return __hip_atomic_load((u64*)p, __ATOMIC_RELAXED, __HIP_MEMORY_SCOPE_AGENT);
}
__device__ __forceinline__ void st_rec(u64* p, u64 v) {
  __hip_atomic_store(p, v, __ATOMIC_RELAXED, __HIP_MEMORY_SCOPE_AGENT);
}
__device__ __forceinline__ u64 pack(float h, u32 ep) {
  return ((u64)ep << 32) | (u64)__float_as_uint(h);
}

// Poll this thread's 4 records of one slot until epoch matches, then deposit
// the floats into LDS. All 4 loads independent -> one RT per retry.
__device__ __forceinline__ void poll_stage(const u64* rec, u32 ep,
                                           float* lds, int tid) {
  u64 v0, v1, v2, v3;
  for (;;) {
    v0 = ld_rec(rec + tid);
    v1 = ld_rec(rec + tid + NTHR);
    v2 = ld_rec(rec + tid + 2 * NTHR);
    v3 = ld_rec(rec + tid + 3 * NTHR);
    if ((u32)(v0 >> 32) == ep && (u32)(v1 >> 32) == ep &&
        (u32)(v2 >> 32) == ep && (u32)(v3 >> 32) == ep) break;
    __builtin_amdgcn_s_sleep(1);
  }
  lds[tid           ] = __uint_as_float((u32)v0);
  lds[tid +     NTHR] = __uint_as_float((u32)v1);
  lds[tid + 2 * NTHR] = __uint_as_float((u32)v2);
  lds[tid + 3 * NTHR] = __uint_as_float((u32)v3);
}

// Same for two slots at once (8 loads in flight) — keeps the h2 chain at
// one observe-RT per step instead of two.
__device__ __forceinline__ void poll_stage2(const u64* recA, u32 epA,
                                            const u64* recB, u32 epB,
                                            float* ldsA, float* ldsB, int tid) {
  u64 a0, a1, a2, a3, b0, b1, b2, b3;
  for (;;) {
    a0 = ld_rec(recA + tid);
    a1 = ld_rec(recA + tid + NTHR);
    a2 = ld_rec(recA + tid + 2 * NTHR);
    a3 = ld_rec(recA + tid + 3 * NTHR);
    b0 = ld_rec(recB + tid);
    b1 = ld_rec(recB + tid + NTHR);
    b2 = ld_rec(recB + tid + 2 * NTHR);
    b3 = ld_rec(recB + tid + 3 * NTHR);
    if ((u32)(a0 >> 32) == epA && (u32)(a1 >> 32) == epA &&
        (u32)(a2 >> 32) == epA && (u32)(a3 >> 32) == epA &&
        (u32)(b0 >> 32) == epB && (u32)(b1 >> 32) == epB &&
        (u32)(b2 >> 32) == epB && (u32)(b3 >> 32) == epB) break;
    __builtin_amdgcn_s_sleep(1);
  }
  ldsA[tid           ] = __uint_as_float((u32)a0);
  ldsA[tid +     NTHR] = __uint_as_float((u32)a1);
  ldsA[tid + 2 * NTHR] = __uint_as_float((u32)a2);
  ldsA[tid + 3 * NTHR] = __uint_as_float((u32)a3);
  ldsB[tid           ] = __uint_as_float((u32)b0);
  ldsB[tid +     NTHR] = __uint_as_float((u32)b1);
  ldsB[tid + 2 * NTHR] = __uint_as_float((u32)b2);
  ldsB[tid + 3 * NTHR] = __uint_as_float((u32)b3);
}

// Zero all record epochs before each run (agent-scope stores: must be
// visible to the main kernel's L2-bypassing sc1 loads).
__global__ void init_kernel() {
  int i = blockIdx.x * blockDim.x + threadIdx.x;
  int n = gridDim.x * blockDim.x;
  for (int k = i; k < NSLOT * DH; k += n) {
    st_rec(&gR1[k], 0ull);
    st_rec(&gR2[k], 0ull);
  }
}

__global__ __launch_bounds__(NTHR, 2)
void rnn2_kernel(const float* __restrict__ X,
                 const float* __restrict__ Wa, const float* __restrict__ ba,
                 const float* __restrict__ Wb, const float* __restrict__ bb,
                 const float* __restrict__ Wc, const float* __restrict__ bc,
                 const float* __restrict__ Wd, const float* __restrict__ bd,
                 const float* __restrict__ Wo, const float* __restrict__ bo,
                 float* __restrict__ out)
{
  const int g   = blockIdx.x;
  const int tid = threadIdx.x;
  const int w   = tid >> 6;   // wave
  const int l   = tid & 63;   // lane

  // Double-buffered staging: stage(t) writes parity (t-1)&1 [h1] / t&1 [h2];
  // one barrier per step between stage and dot. Wave skew within a WG is
  // bounded by that barrier, so distance-2 buffer reuse is race-free.
  __shared__ float sA[2][DH];
  __shared__ float sB[2][DH];

  if (g < HALF) {
    // ================= h1 chain (+ output epilogue) =================
    const int r0 = g * 16 + 2 * w, r1 = r0 + 1;   // my two h1 rows
    float4 wA0[4], wA1[4], wB0[8], wB1[8], wO[8];
    {
      const float4* p0 = (const float4*)(Wa + (size_t)r0 * DIN);
      const float4* p1 = (const float4*)(Wa + (size_t)r1 * DIN);
      #pragma unroll
      for (int j = 0; j < 4; ++j) { wA0[j] = p0[l + 64 * j]; wA1[j] = p1[l + 64 * j]; }
    }
    {
      const float4* p0 = (const float4*)(Wb + (size_t)r0 * DH);
      const float4* p1 = (const float4*)(Wb + (size_t)r1 * DH);
      #pragma unroll
      for (int j = 0; j < 8; ++j) { wB0[j] = p0[l + 64 * j]; wB1[j] = p1[l + 64 * j]; }
    }
    const int orow = g * 8 + w;                   // my output row
    {
      const float4* p = (const float4*)(Wo + (size_t)orow * DH);
      #pragma unroll
      for (int j = 0; j < 8; ++j) wO[j] = p[l + 64 * j];
    }
    const float b1_0 = ba[r0] + bb[r0];
    const float b1_1 = ba[r1] + bb[r1];
    const float bo_r = bo[orow];

    for (int t = 1; t <= TT; ++t) {
      // A.x[t-1]: no cross-WG dependency — compute before the wait
      float a0 = 0.f, a1 = 0.f;
      {
        const float4* px = (const float4*)(X + (size_t)(t - 1) * DIN);
        #pragma unroll
        for (int j = 0; j < 4; ++j) {
          float4 x4 = px[l + 64 * j];
          a0 += dot4(wA0[j], x4);
          a1 += dot4(wA1[j], x4);
        }
      }
      if (t > 1) {
        float* buf = sA[(t - 1) & 1];
        poll_stage(gR1 + (size_t)(t - 1) * DH, (u32)(t - 1), buf, tid);
        __syncthreads();
        const float4* ph = (const float4*)buf;
        #pragma unroll
        for (int j = 0; j < 8; ++j) {
          float4 h4 = ph[l + 64 * j];
          a0 += dot4(wB0[j], h4);
          a1 += dot4(wB1[j], h4);
        }
      }
      a0 = wave_sum(a0); a1 = wave_sum(a1);
      if (l == 0) {   // publish: two fire-and-forget atomic u64 records
        u64* dst = gR1 + (size_t)t * DH;
        st_rec(dst + r0, pack(tanhf(a0 + b1_0), (u32)t));
        st_rec(dst + r1, pack(tanhf(a1 + b1_1), (u32)t));
      }
    }

    // ---- epilogue: out = Wo . h2[TT] + bo (1 row per wave) ----
    // sA[0] has parity != the loop's last dot buffer (sA[1]) -> race-free.
    poll_stage(gR2 + (size_t)TT * DH, (u32)TT, sA[0], tid);
    __syncthreads();
    {
      const float4* ph = (const float4*)sA[0];
      float acc = 0.f;
      #pragma unroll
      for (int j = 0; j < 8; ++j) acc += dot4(wO[j], ph[l + 64 * j]);
      acc = wave_sum(acc);
      if (l == 0) out[orow] = acc + bo_r;
    }
  } else {
    // ========================= h2 chain =========================
    const int gg = g - HALF;
    const int r0 = gg * 16 + 2 * w, r1 = r0 + 1;  // my two h2 rows
    float4 wC0[8], wC1[8], wD0[8], wD1[8];
    {
      const float4* p0 = (const float4*)(Wc + (size_t)r0 * DH);
      const float4* p1 = (const float4*)(Wc + (size_t)r1 * DH);
      #pragma unroll
      for (int j = 0; j < 8; ++j) { wC0[j] = p0[l + 64 * j]; wC1[j] = p1[l + 64 * j]; }
    }
    {
      const float4* p0 = (const float4*)(Wd + (size_t)r0 * DH);
      const float4* p1 = (const float4*)(Wd + (size_t)r1 * DH);
      #pragma unroll
      for (int j = 0; j < 8; ++j) { wD0[j] = p0[l + 64 * j]; wD1[j] = p1[l + 64 * j]; }
    }
    const float b2_0 = bc[r0] + bd[r0];
    const float b2_1 = bc[r1] + bd[r1];

    for (int t = 1; t <= TT; ++t) {
      float* bufA = sA[t & 1];
      float* bufB = sB[t & 1];
      if (t > 1)
        poll_stage2(gR1 + (size_t)t * DH, (u32)t,
                    gR2 + (size_t)(t - 1) * DH, (u32)(t - 1), bufA, bufB, tid);
      else
        poll_stage(gR1 + (size_t)t * DH, (u32)t, bufA, tid);
      __syncthreads();

      float a0 = 0.f, a1 = 0.f;
      {
        const float4* ph = (const float4*)bufA;
        #pragma unroll
        for (int j = 0; j < 8; ++j) {
          float4 h4 = ph[l + 64 * j];
          a0 += dot4(wC0[j], h4);
          a1 += dot4(wC1[j], h4);
        }
      }
      if (t > 1) {
        const float4* ph = (const float4*)bufB;
        #pragma unroll
        for (int j = 0; j < 8; ++j) {
          float4 h4 = ph[l + 64 * j];
          a0 += dot4(wD0[j], h4);
          a1 += dot4(wD1[j], h4);
        }
      }
      a0 = wave_sum(a0); a1 = wave_sum(a1);
      if (l == 0) {
        u64* dst = gR2 + (size_t)t * DH;
        st_rec(dst + r0, pack(tanhf(a0 + b2_0), (u32)t));
        st_rec(dst + r1, pack(tanhf(a1 + b2_1), (u32)t));
      }
    }
  }
}

extern "C" void kernel_launch(void* const* d_in, const int* in_sizes, int n_in,
                              void* d_out, int out_size, void* d_ws, size_t ws_size,
                              hipStream_t stream)
{
  (void)in_sizes; (void)n_in; (void)out_size; (void)d_ws; (void)ws_size;

  const float* X  = (const float*)d_in[0];
  const float* Wa = (const float*)d_in[1];   // W_i2h1 [H][IN]
  const float* ba = (const float*)d_in[2];
  const float* Wb = (const float*)d_in[3];   // W_h2h1 [H][H]
  const float* bb = (const float*)d_in[4];
  // d_in[5], d_in[6]: W_h2o1 / b_h2o1 — dead code in the reference
  const float* Wc = (const float*)d_in[7];   // W_i2h2 [H][H]
  const float* bc = (const float*)d_in[8];
  const float* Wd = (const float*)d_in[9];   // W_h2h2 [H][H]
  const float* bd = (const float*)d_in[10];
  const float* Wo = (const float*)d_in[11];  // W_h2o2 [OUT][H]
  const float* bo = (const float*)d_in[12];
  float* out = (float*)d_out;

  init_kernel<<<dim3(1024), dim3(256), 0, stream>>>();

  void* args[] = { &X, &Wa, &ba, &Wb, &bb, &Wc, &bc, &Wd, &bd, &Wo, &bo, &out };
  (void)hipLaunchCooperativeKernel((void*)rnn2_kernel, dim3(NWG), dim3(NTHR),
                                   args, 0, stream);
}